// Round 10
// baseline (201.034 us; speedup 1.0000x reference)
//
#include <hip/hip_runtime.h>

// SSIM loss, fused. Input: enhanced, target fp32 [16,3,512,512]. Output: scalar fp32.
// V11 = V10 (row-chain, single LDS buffer, lgkm-only barriers, register prefetch,
// 4ch pk_fma, item8) + two changes:
//  (1) interleaved float4 LDS layout (mu1,mu2,S,XY per col) with low-bit XOR
//      swizzle slot(c) = c ^ ((c>>3)&7): v-pass = 10 ds_read_b128 (was 20 b64),
//      h-write start-banks 8-way -> 2-way (optimal for b128).
//  (2) fused finish: atomic sum + ticket counter; last block writes out[0].
//      Reduce kernel removed; ws[0..7] zeroed via hipMemsetAsync.

#define TILE_W 64
#define TILE_H 16
#define HALO 3
#define IN_H 22                      // TILE_H + 2*HALO
#define ROW_SLOTS 66                 // float4 slots/row; 264 words, 264%32=8
#define IMG_H 512
#define IMG_W 512
#define NPLANES 48                   // 16 * 3
#define NTX 8                        // x-tiles per row chain
#define NB_TOTAL (32 * NPLANES)      // 1536 blocks
#define SSIM_C1 1.0e-4f
#define SSIM_C2 9.0e-4f

static __device__ constexpr float G[7] = {
    0.03663284536f, 0.11128076166f, 0.21674531251f, 0.27068216094f,
    0.21674531251f, 0.11128076166f, 0.03663284536f};

// Packed fp32 FMA: d.lo = fma(a.lo,b.lo,c.lo), d.hi = fma(a.hi,b.hi,c.hi).
__device__ __forceinline__ float2 pk_fma(const float2 a, const float2 b,
                                         const float2 c) {
  float2 d;
  asm("v_pk_fma_f32 %0, %1, %2, %3" : "=v"(d) : "v"(a), "v"(b), "v"(c));
  return d;
}

// Aligned float4 load with zero fill outside [0, IMG_W). col is a multiple of 4.
__device__ __forceinline__ float4 ld4z(const float* __restrict__ row, int col) {
  if (col >= 0 && col + 3 < IMG_W) {
    return *reinterpret_cast<const float4*>(row + col);
  }
  float4 v;
  v.x = ((unsigned)(col + 0) < IMG_W) ? row[col + 0] : 0.f;
  v.y = ((unsigned)(col + 1) < IMG_W) ? row[col + 1] : 0.f;
  v.z = ((unsigned)(col + 2) < IMG_W) ? row[col + 2] : 0.f;
  v.w = ((unsigned)(col + 3) < IMG_W) ? row[col + 3] : 0.f;
  return v;
}

// Barrier that keeps prefetch global loads in flight: wait LDS ops only.
__device__ __forceinline__ void lds_barrier() {
  __builtin_amdgcn_sched_barrier(0);
  asm volatile("s_waitcnt lgkmcnt(0)" ::: "memory");
  __builtin_amdgcn_s_barrier();
  __builtin_amdgcn_sched_barrier(0);
}

__global__ __launch_bounds__(256, 4) void ssim_row_kernel(
    const float* __restrict__ x, const float* __restrict__ y,
    float* __restrict__ ws, float* __restrict__ out) {
  // One float4 = (mu1, mu2, S, XY) per (row, swizzled col). 23,232 B.
  __shared__ __align__(16) float4 hbuf[IN_H][ROW_SLOTS];

  const int tid = threadIdx.x;
  const int ty = blockIdx.x;           // 32 tile-rows
  const int plane = blockIdx.y;        // 48 planes
  const float* __restrict__ xp = x + (size_t)plane * (IMG_H * IMG_W);
  const float* __restrict__ yp = y + (size_t)plane * (IMG_H * IMG_W);
  const int y0 = ty * TILE_H - HALO;
  const bool edge_y = (ty == 0) | (ty == 31);

  // h-pass item8: thread t<176 owns (row t>>3, 8-col group t&7).
  const int hr = tid >> 3;
  const int cg = tid & 7;
  const bool active = tid < IN_H * 8;  // 176
  const int gy = y0 + hr;

  float4 px[4], py[4];  // prefetched 16-float window per image

  // Issue global loads for tile tx into px/py.
  auto load_tile = [&](int tx) {
    const int bcol = tx * TILE_W + 8 * cg - 4;
    const bool edge = edge_y | (tx == 0) | (tx == NTX - 1);
    if (!edge) {
      const float* xr = xp + (size_t)gy * IMG_W + bcol;
      const float* yr = yp + (size_t)gy * IMG_W + bcol;
#pragma unroll
      for (int v = 0; v < 4; ++v) {
        px[v] = *reinterpret_cast<const float4*>(xr + 4 * v);
        py[v] = *reinterpret_cast<const float4*>(yr + 4 * v);
      }
    } else if ((unsigned)gy < IMG_H) {
      const float* xr = xp + (size_t)gy * IMG_W;
      const float* yr = yp + (size_t)gy * IMG_W;
#pragma unroll
      for (int v = 0; v < 4; ++v) {
        px[v] = ld4z(xr, bcol + 4 * v);
        py[v] = ld4z(yr, bcol + 4 * v);
      }
    } else {
      const float4 z = make_float4(0.f, 0.f, 0.f, 0.f);
#pragma unroll
      for (int v = 0; v < 4; ++v) { px[v] = z; py[v] = z; }
    }
  };

  // Horizontal 7-tap over the prefetched window. Write col C=8cg+j to slot
  // 8cg + (j^cg): byte offset (j<<4)^(cg<<4) off the group base. Start banks
  // within a 16-lane window: (8hr + 4(j^cg))%32 -> each bank hit 2x = optimal.
  auto h_pass = [&]() {
    const float wx[16] = {px[0].x, px[0].y, px[0].z, px[0].w,
                          px[1].x, px[1].y, px[1].z, px[1].w,
                          px[2].x, px[2].y, px[2].z, px[2].w,
                          px[3].x, px[3].y, px[3].z, px[3].w};
    const float wy[16] = {py[0].x, py[0].y, py[0].z, py[0].w,
                          py[1].x, py[1].y, py[1].z, py[1].w,
                          py[2].x, py[2].y, py[2].z, py[2].w,
                          py[3].x, py[3].y, py[3].z, py[3].w};
    float2 A[8], B[8];
#pragma unroll
    for (int j = 0; j < 8; ++j) {
      A[j] = make_float2(0.f, 0.f);
      B[j] = make_float2(0.f, 0.f);
    }
#pragma unroll
    for (int wi = 1; wi < 15; ++wi) {
      const float xv = wx[wi];
      const float yv = wy[wi];
      const float2 xyp = make_float2(xv, yv);
      const float2 spp = make_float2(fmaf(xv, xv, yv * yv), xv * yv);
#pragma unroll
      for (int j = 0; j < 8; ++j) {
        const int k = wi - 1 - j;  // tap index for output col j
        if (k >= 0 && k < 7) {
          const float2 gk2 = make_float2(G[k], G[k]);
          A[j] = pk_fma(gk2, xyp, A[j]);
          B[j] = pk_fma(gk2, spp, B[j]);
        }
      }
    }
    char* wbase = reinterpret_cast<char*>(&hbuf[hr][cg * 8]);
    const int cgx = cg << 4;
#pragma unroll
    for (int j = 0; j < 8; ++j) {
      *reinterpret_cast<float4*>(wbase + ((j << 4) ^ cgx)) =
          make_float4(A[j].x, A[j].y, B[j].x, B[j].y);
    }
  };

  // Vertical 7-tap + SSIM map; thread = (col tid&63, 4 rows). One b128 per
  // input row delivers all 4 channels; slot(c) matches the writer's swizzle.
  const int c = tid & 63;
  const int slotc = c ^ ((c >> 3) & 7);
  const int r0 = (tid >> 6) * 4;
  auto v_pass = [&]() -> float {
    const float4* hb = &hbuf[r0][slotc];
    float2 M[4], S4[4];
#pragma unroll
    for (int t = 0; t < 4; ++t) {
      M[t] = make_float2(0.f, 0.f);
      S4[t] = make_float2(0.f, 0.f);
    }
#pragma unroll
    for (int j = 0; j < 10; ++j) {  // rows r0+j, immediate offsets j*1056B
      const float4 v = hb[j * ROW_SLOTS];
      const float2 mv = make_float2(v.x, v.y);
      const float2 sv = make_float2(v.z, v.w);
#pragma unroll
      for (int t = 0; t < 4; ++t) {
        const int k = j - t;  // tap index for output row r0+t
        if (k >= 0 && k < 7) {
          const float2 gk2 = make_float2(G[k], G[k]);
          M[t] = pk_fma(gk2, mv, M[t]);
          S4[t] = pk_fma(gk2, sv, S4[t]);
        }
      }
    }
    float a = 0.f;
#pragma unroll
    for (int t = 0; t < 4; ++t) {
      const float mu1 = M[t].x, mu2 = M[t].y;
      const float mu12 = mu1 * mu2;
      const float msq = fmaf(mu1, mu1, mu2 * mu2);  // mu1^2 + mu2^2
      const float sig12 = S4[t].y - mu12;
      const float sigsum = S4[t].x - msq;           // sigma1 + sigma2
      const float num = fmaf(2.f, mu12, SSIM_C1) * fmaf(2.f, sig12, SSIM_C2);
      const float den = (msq + SSIM_C1) * (sigsum + SSIM_C2);
      float r = __builtin_amdgcn_rcpf(den);  // den > 0 always
      r = r * fmaf(-den, r, 2.f);            // 1 Newton step, ~1 ulp
      a = fmaf(num, r, a);
    }
    return a;
  };

  float acc = 0.f;
  if (active) load_tile(0);
#pragma unroll 2
  for (int q = 0; q < NTX; ++q) {
    if (active) {
      h_pass();                           // consumes prefetch
      if (q < NTX - 1) load_tile(q + 1);  // issue next tile's loads
    }
    lds_barrier();   // h-writes visible; prefetch global loads stay in flight
    acc += v_pass();
    lds_barrier();   // v-reads done before next tile's h-writes reuse buffer
  }

  // Block reduction once per row-chain, then fused global finish.
#pragma unroll
  for (int off = 32; off > 0; off >>= 1) acc += __shfl_down(acc, off, 64);
  __shared__ float wsum[4];
  if ((tid & 63) == 0) wsum[tid >> 6] = acc;
  __syncthreads();
  if (tid == 0) {
    const float s = wsum[0] + wsum[1] + wsum[2] + wsum[3];
    atomicAdd(&ws[0], s);                 // device-scope by default
    __threadfence();
    const unsigned prev =
        atomicAdd(reinterpret_cast<unsigned*>(ws) + 1, 1u);
    if (prev == NB_TOTAL - 1) {           // last block finishes the loss
      __threadfence();
      const float tot = atomicAdd(&ws[0], 0.0f);  // coherent read
      out[0] = 1.f - tot * (1.f / (float)(NPLANES * IMG_H * IMG_W));
    }
  }
}

extern "C" void kernel_launch(void* const* d_in, const int* in_sizes, int n_in,
                              void* d_out, int out_size, void* d_ws, size_t ws_size,
                              hipStream_t stream) {
  const float* enhanced = (const float*)d_in[0];
  const float* target = (const float*)d_in[1];
  float* out = (float*)d_out;
  float* ws = (float*)d_ws;

  hipMemsetAsync(d_ws, 0, 8, stream);     // sum + ticket counter
  dim3 grid(IMG_H / TILE_H, NPLANES, 1);  // 32 x 48 = 1536 row-chain blocks
  dim3 block(256, 1, 1);
  ssim_row_kernel<<<grid, block, 0, stream>>>(enhanced, target, ws, out);
}

// Round 11
// 142.650 us; speedup vs baseline: 1.4093x; 1.4093x over previous
//
#include <hip/hip_runtime.h>

// SSIM loss, fused. Input: enhanced, target fp32 [16,3,512,512]. Output: scalar fp32.
// V12 = V11's LDS layout (interleaved float4 (mu1,mu2,S,XY), XOR swizzle
// slot(c)=c^((c>>3)&7): zero bank conflicts measured) + V10's two-kernel tail
// (per-block partial + tiny reduce kernel). V11's fused atomic finish appended
// ~56us of serialized same-address atomic tail -- removed.

#define TILE_W 64
#define TILE_H 16
#define HALO 3
#define IN_H 22                      // TILE_H + 2*HALO
#define ROW_SLOTS 66                 // float4 slots/row; 264 words, 264%32=8
#define IMG_H 512
#define IMG_W 512
#define NPLANES 48                   // 16 * 3
#define NTX 8                        // x-tiles per row chain
#define SSIM_C1 1.0e-4f
#define SSIM_C2 9.0e-4f

static __device__ constexpr float G[7] = {
    0.03663284536f, 0.11128076166f, 0.21674531251f, 0.27068216094f,
    0.21674531251f, 0.11128076166f, 0.03663284536f};

// Packed fp32 FMA: d.lo = fma(a.lo,b.lo,c.lo), d.hi = fma(a.hi,b.hi,c.hi).
__device__ __forceinline__ float2 pk_fma(const float2 a, const float2 b,
                                         const float2 c) {
  float2 d;
  asm("v_pk_fma_f32 %0, %1, %2, %3" : "=v"(d) : "v"(a), "v"(b), "v"(c));
  return d;
}

// Aligned float4 load with zero fill outside [0, IMG_W). col is a multiple of 4.
__device__ __forceinline__ float4 ld4z(const float* __restrict__ row, int col) {
  if (col >= 0 && col + 3 < IMG_W) {
    return *reinterpret_cast<const float4*>(row + col);
  }
  float4 v;
  v.x = ((unsigned)(col + 0) < IMG_W) ? row[col + 0] : 0.f;
  v.y = ((unsigned)(col + 1) < IMG_W) ? row[col + 1] : 0.f;
  v.z = ((unsigned)(col + 2) < IMG_W) ? row[col + 2] : 0.f;
  v.w = ((unsigned)(col + 3) < IMG_W) ? row[col + 3] : 0.f;
  return v;
}

// Barrier that keeps prefetch global loads in flight: wait LDS ops only.
__device__ __forceinline__ void lds_barrier() {
  __builtin_amdgcn_sched_barrier(0);
  asm volatile("s_waitcnt lgkmcnt(0)" ::: "memory");
  __builtin_amdgcn_s_barrier();
  __builtin_amdgcn_sched_barrier(0);
}

__global__ __launch_bounds__(256, 4) void ssim_row_kernel(
    const float* __restrict__ x, const float* __restrict__ y,
    float* __restrict__ partial) {
  // One float4 = (mu1, mu2, S, XY) per (row, swizzled col). 23,232 B.
  __shared__ __align__(16) float4 hbuf[IN_H][ROW_SLOTS];

  const int tid = threadIdx.x;
  const int ty = blockIdx.x;           // 32 tile-rows
  const int plane = blockIdx.y;        // 48 planes
  const float* __restrict__ xp = x + (size_t)plane * (IMG_H * IMG_W);
  const float* __restrict__ yp = y + (size_t)plane * (IMG_H * IMG_W);
  const int y0 = ty * TILE_H - HALO;
  const bool edge_y = (ty == 0) | (ty == 31);

  // h-pass item8: thread t<176 owns (row t>>3, 8-col group t&7).
  const int hr = tid >> 3;
  const int cg = tid & 7;
  const bool active = tid < IN_H * 8;  // 176
  const int gy = y0 + hr;

  float4 px[4], py[4];  // prefetched 16-float window per image

  // Issue global loads for tile tx into px/py.
  auto load_tile = [&](int tx) {
    const int bcol = tx * TILE_W + 8 * cg - 4;
    const bool edge = edge_y | (tx == 0) | (tx == NTX - 1);
    if (!edge) {
      const float* xr = xp + (size_t)gy * IMG_W + bcol;
      const float* yr = yp + (size_t)gy * IMG_W + bcol;
#pragma unroll
      for (int v = 0; v < 4; ++v) {
        px[v] = *reinterpret_cast<const float4*>(xr + 4 * v);
        py[v] = *reinterpret_cast<const float4*>(yr + 4 * v);
      }
    } else if ((unsigned)gy < IMG_H) {
      const float* xr = xp + (size_t)gy * IMG_W;
      const float* yr = yp + (size_t)gy * IMG_W;
#pragma unroll
      for (int v = 0; v < 4; ++v) {
        px[v] = ld4z(xr, bcol + 4 * v);
        py[v] = ld4z(yr, bcol + 4 * v);
      }
    } else {
      const float4 z = make_float4(0.f, 0.f, 0.f, 0.f);
#pragma unroll
      for (int v = 0; v < 4; ++v) { px[v] = z; py[v] = z; }
    }
  };

  // Horizontal 7-tap over the prefetched window. Write col C=8cg+j to slot
  // 8cg + (j^cg): byte offset (j<<4)^(cg<<4) off the group base. Start banks
  // within a 16-lane window: (8hr + 4(j^cg))%32 -> each bank hit 2x = optimal.
  auto h_pass = [&]() {
    const float wx[16] = {px[0].x, px[0].y, px[0].z, px[0].w,
                          px[1].x, px[1].y, px[1].z, px[1].w,
                          px[2].x, px[2].y, px[2].z, px[2].w,
                          px[3].x, px[3].y, px[3].z, px[3].w};
    const float wy[16] = {py[0].x, py[0].y, py[0].z, py[0].w,
                          py[1].x, py[1].y, py[1].z, py[1].w,
                          py[2].x, py[2].y, py[2].z, py[2].w,
                          py[3].x, py[3].y, py[3].z, py[3].w};
    float2 A[8], B[8];
#pragma unroll
    for (int j = 0; j < 8; ++j) {
      A[j] = make_float2(0.f, 0.f);
      B[j] = make_float2(0.f, 0.f);
    }
#pragma unroll
    for (int wi = 1; wi < 15; ++wi) {
      const float xv = wx[wi];
      const float yv = wy[wi];
      const float2 xyp = make_float2(xv, yv);
      const float2 spp = make_float2(fmaf(xv, xv, yv * yv), xv * yv);
#pragma unroll
      for (int j = 0; j < 8; ++j) {
        const int k = wi - 1 - j;  // tap index for output col j
        if (k >= 0 && k < 7) {
          const float2 gk2 = make_float2(G[k], G[k]);
          A[j] = pk_fma(gk2, xyp, A[j]);
          B[j] = pk_fma(gk2, spp, B[j]);
        }
      }
    }
    char* wbase = reinterpret_cast<char*>(&hbuf[hr][cg * 8]);
    const int cgx = cg << 4;
#pragma unroll
    for (int j = 0; j < 8; ++j) {
      *reinterpret_cast<float4*>(wbase + ((j << 4) ^ cgx)) =
          make_float4(A[j].x, A[j].y, B[j].x, B[j].y);
    }
  };

  // Vertical 7-tap + SSIM map; thread = (col tid&63, 4 rows). One b128 per
  // input row delivers all 4 channels; slot(c) matches the writer's swizzle.
  const int c = tid & 63;
  const int slotc = c ^ ((c >> 3) & 7);
  const int r0 = (tid >> 6) * 4;
  auto v_pass = [&]() -> float {
    const float4* hb = &hbuf[r0][slotc];
    float2 M[4], S4[4];
#pragma unroll
    for (int t = 0; t < 4; ++t) {
      M[t] = make_float2(0.f, 0.f);
      S4[t] = make_float2(0.f, 0.f);
    }
#pragma unroll
    for (int j = 0; j < 10; ++j) {  // rows r0+j, immediate offsets j*1056B
      const float4 v = hb[j * ROW_SLOTS];
      const float2 mv = make_float2(v.x, v.y);
      const float2 sv = make_float2(v.z, v.w);
#pragma unroll
      for (int t = 0; t < 4; ++t) {
        const int k = j - t;  // tap index for output row r0+t
        if (k >= 0 && k < 7) {
          const float2 gk2 = make_float2(G[k], G[k]);
          M[t] = pk_fma(gk2, mv, M[t]);
          S4[t] = pk_fma(gk2, sv, S4[t]);
        }
      }
    }
    float a = 0.f;
#pragma unroll
    for (int t = 0; t < 4; ++t) {
      const float mu1 = M[t].x, mu2 = M[t].y;
      const float mu12 = mu1 * mu2;
      const float msq = fmaf(mu1, mu1, mu2 * mu2);  // mu1^2 + mu2^2
      const float sig12 = S4[t].y - mu12;
      const float sigsum = S4[t].x - msq;           // sigma1 + sigma2
      const float num = fmaf(2.f, mu12, SSIM_C1) * fmaf(2.f, sig12, SSIM_C2);
      const float den = (msq + SSIM_C1) * (sigsum + SSIM_C2);
      float r = __builtin_amdgcn_rcpf(den);  // den > 0 always
      r = r * fmaf(-den, r, 2.f);            // 1 Newton step, ~1 ulp
      a = fmaf(num, r, a);
    }
    return a;
  };

  float acc = 0.f;
  if (active) load_tile(0);
#pragma unroll 2
  for (int q = 0; q < NTX; ++q) {
    if (active) {
      h_pass();                           // consumes prefetch
      if (q < NTX - 1) load_tile(q + 1);  // issue next tile's loads
    }
    lds_barrier();   // h-writes visible; prefetch global loads stay in flight
    acc += v_pass();
    lds_barrier();   // v-reads done before next tile's h-writes reuse buffer
  }

  // Block reduction once per row-chain (8 tiles accumulated per thread).
#pragma unroll
  for (int off = 32; off > 0; off >>= 1) acc += __shfl_down(acc, off, 64);
  __shared__ float wsum[4];
  if ((tid & 63) == 0) wsum[tid >> 6] = acc;
  __syncthreads();
  if (tid == 0) {
    partial[(size_t)plane * 32 + ty] = wsum[0] + wsum[1] + wsum[2] + wsum[3];
  }
}

__global__ __launch_bounds__(1024) void ssim_reduce_kernel(
    const float* __restrict__ partial, int n, float* __restrict__ out) {
  float acc = 0.f;
  const int nv = n >> 2;  // n = 1536 -> 384 float4
  const float4* __restrict__ p4 = reinterpret_cast<const float4*>(partial);
  for (int i = threadIdx.x; i < nv; i += 1024) {
    const float4 v = p4[i];
    acc += (v.x + v.y) + (v.z + v.w);
  }
#pragma unroll
  for (int off = 32; off > 0; off >>= 1) acc += __shfl_down(acc, off, 64);
  __shared__ float wsum[16];
  if ((threadIdx.x & 63) == 0) wsum[threadIdx.x >> 6] = acc;
  __syncthreads();
  if (threadIdx.x == 0) {
    float s = 0.f;
#pragma unroll
    for (int w = 0; w < 16; ++w) s += wsum[w];
    out[0] = 1.f - s * (1.f / (float)(NPLANES * IMG_H * IMG_W));
  }
}

extern "C" void kernel_launch(void* const* d_in, const int* in_sizes, int n_in,
                              void* d_out, int out_size, void* d_ws, size_t ws_size,
                              hipStream_t stream) {
  const float* enhanced = (const float*)d_in[0];
  const float* target = (const float*)d_in[1];
  float* out = (float*)d_out;
  float* partial = (float*)d_ws;

  dim3 grid(IMG_H / TILE_H, NPLANES, 1);  // 32 x 48 = 1536 row-chain blocks
  dim3 block(256, 1, 1);
  ssim_row_kernel<<<grid, block, 0, stream>>>(enhanced, target, partial);

  const int nblocks = (IMG_H / TILE_H) * NPLANES;  // 1536
  ssim_reduce_kernel<<<1, 1024, 0, stream>>>(partial, nblocks, out);
}